// Round 3
// baseline (553.127 us; speedup 1.0000x reference)
//
#include <hip/hip_runtime.h>

// FullAttention fwd: BH=32, T=2048, D=128, fp32 in/out, key_padding_mask (True=masked).
// Flash-style: 4 waves x 32 q-rows = 128 q/block, KVBLK=64, bf16 MFMA 16x16x32.
// Swapped QK^T (mfma(K,Q)) => softmax lane-local; P stays in-register and feeds PV's
// A-operand; V staged TRANSPOSED in LDS (Vt[d][kv], XOR swizzle) so PV B-fragments are
// plain vector LDS reads using the same slot mapping as the P-pack (layout-cancellation
// safe, like QK^T). No inline asm anywhere. QK^T uses hi/lo bf16 split for fp32-grade
// logits. Mask dtype (bool bytes vs int32) detected in-kernel; no d_ws use.

#define BHN  32
#define TSEQ 2048
#define DDIM 128
#define QB   128   // q rows per block
#define WQ   32    // q rows per wave
#define KB   64    // kv rows per tile
#define NKT  (TSEQ / KB)

typedef __attribute__((ext_vector_type(4))) float f32x4;
typedef __attribute__((ext_vector_type(8))) short s16x8;
typedef __attribute__((ext_vector_type(4))) short s16x4;

__device__ __forceinline__ short f2bf(float x) {
    // round-to-nearest-even f32 -> bf16 (finite inputs only)
    unsigned u = __float_as_uint(x);
    unsigned r = (u + 0x7FFFu + ((u >> 16) & 1u)) >> 16;
    return (short)r;
}
__device__ __forceinline__ float bf2f(short b) {
    return __uint_as_float(((unsigned)(unsigned short)b) << 16);
}

__global__ __launch_bounds__(256, 2)
void attn_fwd(const float* __restrict__ Qg, const float* __restrict__ Kg,
              const float* __restrict__ Vg, const unsigned char* __restrict__ Mg,
              float* __restrict__ Og)
{
    __shared__ __align__(16) unsigned short Klds[KB * DDIM];  // 16KB K hi, XOR-swizzled
    __shared__ __align__(16) unsigned short Klo [KB * DDIM];  // 16KB K lo, same swizzle
    __shared__ __align__(16) unsigned short Vt  [DDIM * KB];  // 16KB V^T: (d,kv), swizzled
    __shared__ float biasLds[KB];
    __shared__ int mflag;

    const int tid  = threadIdx.x;
    const int wave = tid >> 6;
    const int lane = tid & 63;
    const int q16  = lane & 15;
    const int hi   = lane >> 4;

    const int bh    = blockIdx.x;
    const int qbase = blockIdx.y * QB + wave * WQ;

    const float scale = 0.088388347648318447f; // 1/sqrt(128)

    const float* Qp = Qg + ((size_t)bh * TSEQ + qbase) * DDIM;
    const float* Kp = Kg + (size_t)bh * TSEQ * DDIM;
    const float* Vp = Vg + (size_t)bh * TSEQ * DDIM;

    // ---- mask layout detection: probe first 2048 bytes (valid under both layouts).
    // int32 0/1 values -> all bytes at idx%4!=0 are zero; random bool bytes -> ~half set.
    if (tid == 0) mflag = 0;
    __syncthreads();
    {
        int f = 0;
#pragma unroll
        for (int j = 0; j < 8; ++j) {
            const int idx = tid * 8 + j;
            if ((idx & 3) != 0 && Mg[idx] != 0) f = 1;
        }
        if (f) atomicOr(&mflag, 1);
    }
    __syncthreads();
    const int isByte = mflag;   // block-uniform

    // ---- Q fragments (hi/lo): lane holds Q[16qt+q16][32c+8hi+i]*scale ----
    s16x8 qhi[2][4], qlo[2][4];
#pragma unroll
    for (int qt = 0; qt < 2; ++qt) {
        const float* qrow = Qp + (size_t)(qt * 16 + q16) * DDIM;
#pragma unroll
        for (int c = 0; c < 4; ++c) {
            const int d0 = 32 * c + 8 * hi;
            float4 a = *reinterpret_cast<const float4*>(qrow + d0);
            float4 b = *reinterpret_cast<const float4*>(qrow + d0 + 4);
            float x[8] = {a.x, a.y, a.z, a.w, b.x, b.y, b.z, b.w};
            s16x8 fh, fl;
#pragma unroll
            for (int i = 0; i < 8; ++i) {
                const float xs = x[i] * scale;
                const short h = f2bf(xs);
                fh[i] = h;
                fl[i] = f2bf(xs - bf2f(h));
            }
            qhi[qt][c] = fh;
            qlo[qt][c] = fl;
        }
    }

    f32x4 o[2][8];
#pragma unroll
    for (int qt = 0; qt < 2; ++qt)
#pragma unroll
        for (int db = 0; db < 8; ++db)
            o[qt][db] = (f32x4){0.f, 0.f, 0.f, 0.f};
    float mrun[2] = {-1e30f, -1e30f};
    float lrun[2] = {0.f, 0.f};

    // staging assignment: thread covers row srow+8p, d = sd..sd+3
    const int srow = tid >> 5;
    const int sd   = (tid & 31) * 4;

    for (int kt = 0; kt < NKT; ++kt) {
        const int kv0 = kt * KB;
        __syncthreads();   // previous tile's LDS reads done
        if (tid < KB) {
            const size_t mi = (size_t)bh * TSEQ + kv0 + tid;
            const int mv = isByte ? (int)Mg[mi] : ((const int*)Mg)[mi];
            biasLds[tid] = mv ? -1e30f : 0.0f;
        }
#pragma unroll
        for (int p = 0; p < 8; ++p) {
            const int row = srow + p * 8;
            float4 kf = *reinterpret_cast<const float4*>(Kp + (size_t)(kv0 + row) * DDIM + sd);
            float4 vf = *reinterpret_cast<const float4*>(Vp + (size_t)(kv0 + row) * DDIM + sd);
            float kx[4] = {kf.x, kf.y, kf.z, kf.w};
            float vx[4] = {vf.x, vf.y, vf.z, vf.w};
            s16x4 kh4, kl4;
#pragma unroll
            for (int j = 0; j < 4; ++j) {
                const short h = f2bf(kx[j]);
                kh4[j] = h;
                kl4[j] = f2bf(kx[j] - bf2f(h));
            }
            const unsigned ka = ((unsigned)(row * 256 + sd * 2)) ^ ((unsigned)(row & 7) << 4);
            *reinterpret_cast<s16x4*>(reinterpret_cast<char*>(Klds) + ka) = kh4;
            *reinterpret_cast<s16x4*>(reinterpret_cast<char*>(Klo)  + ka) = kl4;
            // V transposed: logical (d, kv=row) at byte ((d*64+kv)*2) ^ ((d&7)<<4)
#pragma unroll
            for (int j = 0; j < 4; ++j) {
                const int d = sd + j;
                const unsigned vb = ((unsigned)((d * KB + row) * 2)) ^ ((unsigned)(d & 7) << 4);
                *reinterpret_cast<unsigned short*>(reinterpret_cast<char*>(Vt) + vb) = (unsigned short)f2bf(vx[j]);
            }
        }
        __syncthreads();

        // ---- S^T = K . Q^T : D[kv][q], acc initialized with mask bias ----
        f32x4 st[2][4];
#pragma unroll
        for (int t = 0; t < 4; ++t) {
            f32x4 binit;
#pragma unroll
            for (int r = 0; r < 4; ++r) binit[r] = biasLds[16 * t + 4 * hi + r];
            st[0][t] = binit;
            st[1][t] = binit;
        }
#pragma unroll
        for (int t = 0; t < 4; ++t) {
#pragma unroll
            for (int c = 0; c < 4; ++c) {
                const unsigned ka =
                    ((unsigned)((16 * t + q16) * 256 + (32 * c + 8 * hi) * 2)) ^
                    ((unsigned)(q16 & 7) << 4);
                s16x8 kh = *reinterpret_cast<const s16x8*>(reinterpret_cast<char*>(Klds) + ka);
                s16x8 kl = *reinterpret_cast<const s16x8*>(reinterpret_cast<char*>(Klo)  + ka);
                st[0][t] = __builtin_amdgcn_mfma_f32_16x16x32_bf16(kh, qhi[0][c], st[0][t], 0, 0, 0);
                st[1][t] = __builtin_amdgcn_mfma_f32_16x16x32_bf16(kh, qhi[1][c], st[1][t], 0, 0, 0);
                st[0][t] = __builtin_amdgcn_mfma_f32_16x16x32_bf16(kh, qlo[0][c], st[0][t], 0, 0, 0);
                st[1][t] = __builtin_amdgcn_mfma_f32_16x16x32_bf16(kh, qlo[1][c], st[1][t], 0, 0, 0);
                st[0][t] = __builtin_amdgcn_mfma_f32_16x16x32_bf16(kl, qhi[0][c], st[0][t], 0, 0, 0);
                st[1][t] = __builtin_amdgcn_mfma_f32_16x16x32_bf16(kl, qhi[1][c], st[1][t], 0, 0, 0);
            }
        }

        // ---- online softmax (lane-local: q = q16 in group qt, kv = 16t + 4hi + r) ----
        s16x8 pf[2][2];
        float resc[2];
#pragma unroll
        for (int qt = 0; qt < 2; ++qt) {
            float mx = st[qt][0][0];
#pragma unroll
            for (int t = 0; t < 4; ++t)
#pragma unroll
                for (int r = 0; r < 4; ++r)
                    mx = fmaxf(mx, st[qt][t][r]);
            mx = fmaxf(mx, __shfl_xor(mx, 16));
            mx = fmaxf(mx, __shfl_xor(mx, 32));
            const float mnew = fmaxf(mrun[qt], mx);
            const float rs   = __expf(mrun[qt] - mnew);
            mrun[qt] = mnew;
            resc[qt] = rs;
            float ps = 0.f;
            float pv[4][4];
#pragma unroll
            for (int t = 0; t < 4; ++t)
#pragma unroll
                for (int r = 0; r < 4; ++r) {
                    const float e = __expf(st[qt][t][r] - mnew);
                    pv[t][r] = e;
                    ps += e;
                }
            ps += __shfl_xor(ps, 16);
            ps += __shfl_xor(ps, 32);
            lrun[qt] = lrun[qt] * rs + ps;
            // pack P (A-operand): frag h slot i: kv = 32h + 16*(i>=4) + 4hi + (i&3)
#pragma unroll
            for (int h = 0; h < 2; ++h) {
                s16x8 f;
#pragma unroll
                for (int r = 0; r < 4; ++r) {
                    f[r]     = f2bf(pv[2 * h][r]);
                    f[r + 4] = f2bf(pv[2 * h + 1][r]);
                }
                pf[qt][h] = f;
            }
        }
        // rescale O: row q' = 4hi + r needs stat from a lane with (lane&15) == q'
#pragma unroll
        for (int qt = 0; qt < 2; ++qt)
#pragma unroll
            for (int r = 0; r < 4; ++r) {
                const int src = (lane & 48) | (4 * hi + r);
                const float rr = __shfl(resc[qt], src);
#pragma unroll
                for (int db = 0; db < 8; ++db)
                    o[qt][db][r] *= rr;
            }

        // ---- PV: o[qt][db] += P . V ; B-fragment slot i must hold
        //      V[kv = 32h + 16*(i>=4) + 4hi + (i&3)][d = 16db + q16]  (matches P-pack) ----
#pragma unroll
        for (int db = 0; db < 8; ++db) {
            const int d = db * 16 + q16;
            const unsigned sw = ((unsigned)(q16 & 7)) << 4;
            s16x8 vfrag[2];
#pragma unroll
            for (int h = 0; h < 2; ++h) {
                const unsigned b0 = ((unsigned)((d * KB + 32 * h + 4 * hi) * 2)) ^ sw;
                const unsigned b1 = ((unsigned)((d * KB + 32 * h + 16 + 4 * hi) * 2)) ^ sw;
                s16x4 lo4 = *reinterpret_cast<const s16x4*>(reinterpret_cast<const char*>(Vt) + b0);
                s16x4 hi4 = *reinterpret_cast<const s16x4*>(reinterpret_cast<const char*>(Vt) + b1);
                s16x8 vv;
                vv[0] = lo4[0]; vv[1] = lo4[1]; vv[2] = lo4[2]; vv[3] = lo4[3];
                vv[4] = hi4[0]; vv[5] = hi4[1]; vv[6] = hi4[2]; vv[7] = hi4[3];
                vfrag[h] = vv;
            }
            o[0][db] = __builtin_amdgcn_mfma_f32_16x16x32_bf16(pf[0][0], vfrag[0], o[0][db], 0, 0, 0);
            o[0][db] = __builtin_amdgcn_mfma_f32_16x16x32_bf16(pf[0][1], vfrag[1], o[0][db], 0, 0, 0);
            o[1][db] = __builtin_amdgcn_mfma_f32_16x16x32_bf16(pf[1][0], vfrag[0], o[1][db], 0, 0, 0);
            o[1][db] = __builtin_amdgcn_mfma_f32_16x16x32_bf16(pf[1][1], vfrag[1], o[1][db], 0, 0, 0);
        }
    }

    // ---- epilogue: normalize by l and store (rows q' = 16qt + 4hi + r) ----
    float* Op = Og + ((size_t)bh * TSEQ + qbase) * DDIM;
#pragma unroll
    for (int qt = 0; qt < 2; ++qt)
#pragma unroll
        for (int r = 0; r < 4; ++r) {
            const int src = (lane & 48) | (4 * hi + r);
            const float inv = 1.0f / __shfl(lrun[qt], src);
            const int qrow = qt * 16 + 4 * hi + r;
#pragma unroll
            for (int db = 0; db < 8; ++db)
                Op[(size_t)qrow * DDIM + db * 16 + q16] = o[qt][db][r] * inv;
        }
}

extern "C" void kernel_launch(void* const* d_in, const int* in_sizes, int n_in,
                              void* d_out, int out_size, void* d_ws, size_t ws_size,
                              hipStream_t stream) {
    const float* q = (const float*)d_in[0];
    const float* k = (const float*)d_in[1];
    const float* v = (const float*)d_in[2];
    const unsigned char* m = (const unsigned char*)d_in[3];
    float* out = (float*)d_out;
    dim3 grid(BHN, TSEQ / QB);   // x = bh fast-varying -> same-head q-blocks share an XCD
    dim3 block(256);
    attn_fwd<<<grid, block, 0, stream>>>(q, k, v, m, out);
}